// Round 4
// baseline (1394.181 us; speedup 1.0000x reference)
//
#include <hip/hip_runtime.h>

// GATClassifier: 2x GATConv(H=16, D=512) + ReLU, mean-pool per graph, linear head.
// N=1024, E=16384 (+N self loops), IN=1300, F=H*D=8192, G=8.
// Round 4: conversion hoisted out of GEMM hot loop. Device pre-pass converts
// A and B to bf16 hi/lo planes stored in chunk-image layout (LDS byte image,
// swizzle + B-transpose + K-tail zeros baked in). GEMM loop: 8 short8 loads +
// 8 ds_write_b128 + 16 ds_read_b128 + 48 MFMA. Fallback to in-loop-conversion
// GEMM (round 3) if ws_size can't hold the planes (~418 MB).

#define NN      1024
#define EE      16384
#define IN_DIM  1300
#define NH      16
#define HD      512
#define FD      8192       // NH*HD
#define NG      8
#define ET      (EE + NN)  // edges incl. self loops
#define SLOPE   0.2f

typedef __attribute__((ext_vector_type(8))) short short8;
typedef __attribute__((ext_vector_type(4))) float f32x4;

// ---------------- CSR build (counting sort by dst) ----------------

__global__ void k_init_counts(int* counts) {
    int i = blockIdx.x * 256 + threadIdx.x;
    if (i < NN) counts[i] = 1;              // self-loop contributes 1
}

__global__ void k_count(const int* __restrict__ dst, int* counts) {
    int e = blockIdx.x * 256 + threadIdx.x;
    if (e < EE) atomicAdd(&counts[dst[e]], 1);
}

__global__ void k_scan(const int* __restrict__ counts, int* __restrict__ off,
                       int* __restrict__ cursor) {
    __shared__ int s[NN];
    int t = threadIdx.x;
    s[t] = counts[t];
    __syncthreads();
    for (int d = 1; d < NN; d <<= 1) {
        int v = (t >= d) ? s[t - d] : 0;
        __syncthreads();
        s[t] += v;
        __syncthreads();
    }
    off[t + 1] = s[t];
    if (t == 0) off[0] = 0;
    cursor[t] = 0;
}

__global__ void k_fill(const int* __restrict__ srcv, const int* __restrict__ dstv,
                       const int* __restrict__ off, int* cursor, int* __restrict__ csr) {
    int e = blockIdx.x * 256 + threadIdx.x;
    if (e < EE) {
        int d = dstv[e];
        int p = atomicAdd(&cursor[d], 1);
        csr[off[d] + p] = srcv[e];
    } else if (e < ET) {
        int n = e - EE;                      // self loop (n,n)
        int p = atomicAdd(&cursor[n], 1);
        csr[off[n] + p] = n;
    }
}

// ---------------- bf16 split helpers + swizzles ----------------

// swizzle for plane path: bank-decorrelates rows r and r+4 on b128 reads.
// XOR touches k bits 3..4 only -> 8-element groups stay contiguous.
__device__ __forceinline__ int swz2(int r) {
    return (((r >> 1) & 3) ^ ((r >> 4) & 3)) << 3;
}
// round-3 swizzle (fallback path only; write+read both use it)
__device__ __forceinline__ int swz(int r) {
    return ((r & 3) ^ ((r >> 4) & 3)) << 3;
}

__device__ __forceinline__ unsigned short bf16_rne(float f) {
    unsigned int u = __float_as_uint(f);
    u += 0x7FFF + ((u >> 16) & 1);
    return (unsigned short)(u >> 16);
}

__device__ __forceinline__ void split2(float f, unsigned short& h, unsigned short& l) {
    unsigned short hh = bf16_rne(f);
    float hf = __uint_as_float(((unsigned int)hh) << 16);
    h = hh;
    l = bf16_rne(f - hf);
}

// ---------------- plane conversion kernels ----------------
// Chunk = LDS image of one 128x32 tile of one plane: ushort L[128][32],
//   A-style: L[r][kc] = val(row0+r, k0 + (kc ^ swz2(r)))      (rows = M)
//   B-style: L[n][kc] = val(k0 + (kc ^ swz2(n)), col0+n)      (rows = N, transposed)
// Chunks ordered [row_tile][k_tile]; k >= K zero-padded (no in-GEMM guards).

__global__ __launch_bounds__(256) void k_conv_a(const float* __restrict__ S,
                                                unsigned short* __restrict__ H,
                                                unsigned short* __restrict__ L,
                                                int K, int KT) {
    const int chunk = blockIdx.x;                 // mt*KT + kt
    const int mt = chunk / KT, kt = chunk - mt * KT;
    const int tid = threadIdx.x;
    const size_t ob = (size_t)chunk * 4096;
#pragma unroll
    for (int half = 0; half < 2; half++) {
        const int r = (tid >> 2) + half * 64;
        const int kc0 = (tid & 3) << 3;
        const int k = kt * 32 + (kc0 ^ swz2(r));  // multiple of 8
        const float* src = S + (size_t)(mt * 128 + r) * K + k;
        float4 f0 = make_float4(0.f, 0.f, 0.f, 0.f), f1 = f0;
        if (k < K)     f0 = *(const float4*)src;        // K%4==0 -> exact
        if (k + 4 < K) f1 = *(const float4*)(src + 4);
        float vals[8] = {f0.x, f0.y, f0.z, f0.w, f1.x, f1.y, f1.z, f1.w};
        short8 hv, lv;
#pragma unroll
        for (int j = 0; j < 8; j++) {
            unsigned short h, l;
            split2(vals[j], h, l);
            hv[j] = (short)h;
            lv[j] = (short)l;
        }
        *(short8*)(H + ob + r * 32 + kc0) = hv;   // coalesced: idx = tid*8
        *(short8*)(L + ob + r * 32 + kc0) = lv;
    }
}

__global__ __launch_bounds__(256) void k_conv_b(const float* __restrict__ S,
                                                unsigned short* __restrict__ H,
                                                unsigned short* __restrict__ L,
                                                int K, int Nn, int KT) {
    __shared__ float T[128][33];                  // transposed fp32 tile
    const int chunk = blockIdx.x;                 // nt*KT + kt
    const int nt = chunk / KT, kt = chunk - nt * KT;
    const int tid = threadIdx.x;
    // phase 1: coalesced read of S[k0..k0+32)[n0..n0+128) -> T[n][k]
    {
        const int kr = tid >> 3;                  // 0..31
        const int c0 = (tid & 7) << 4;            // 0..112
        const int k = kt * 32 + kr;
        const float* row = S + (size_t)k * Nn + nt * 128 + c0;
#pragma unroll
        for (int j = 0; j < 4; j++) {
            float4 v = (k < K) ? *(const float4*)(row + (j << 2))
                               : make_float4(0.f, 0.f, 0.f, 0.f);
            T[c0 + (j << 2) + 0][kr] = v.x;
            T[c0 + (j << 2) + 1][kr] = v.y;
            T[c0 + (j << 2) + 2][kr] = v.z;
            T[c0 + (j << 2) + 3][kr] = v.w;
        }
    }
    __syncthreads();
    const size_t ob = (size_t)chunk * 4096;
#pragma unroll
    for (int half = 0; half < 2; half++) {
        const int n = (tid >> 2) + half * 64;
        const int kc0 = (tid & 3) << 3;
        const int ks = kc0 ^ swz2(n);             // contiguous 8 in T row
        short8 hv, lv;
#pragma unroll
        for (int j = 0; j < 8; j++) {
            unsigned short h, l;
            split2(T[n][ks + j], h, l);
            hv[j] = (short)h;
            lv[j] = (short)l;
        }
        *(short8*)(H + ob + n * 32 + kc0) = hv;
        *(short8*)(L + ob + n * 32 + kc0) = lv;
    }
}

// ---------------- plane-path GEMM ----------------
// C[M=1024, Nn=FD] fp32 = A @ B from pre-split planes, 3 MFMA products
// (Ah*Bh + Ah*Bl + Al*Bh; al*bl term ~2^-18 dropped).
// Block 256 thr (4 waves), tile 128x128, BK=32; wave -> 64x64 quadrant,
// 4x4 fragments of 16x16x32. Verified gfx950 layouts (learn_hip m89/m91/m92):
//   A frag: row = lane&15, k = (lane>>4)*8 + 0..7 ; B frag symmetric (col = lane&15)
//   C/D:    col = lane&15, row = (lane>>4)*4 + reg
// Staging: per K-step each thread copies 2x short8 per plane at linear tid*16B
// (LDS write image == plane chunk image; swizzle already baked in).

__global__ __launch_bounds__(256, 2) void k_gemm_planes(
        const unsigned short* __restrict__ Ahp, const unsigned short* __restrict__ Alp,
        const unsigned short* __restrict__ Bhp, const unsigned short* __restrict__ Blp,
        float* __restrict__ C, int KT, int Nn) {
    __shared__ short smem[4][4096];               // Ah, Al, Bh, Bl images (32 KB)
    const int tid = threadIdx.x;
    const int lane = tid & 63;
    const int wid = tid >> 6;
    const int wr = wid >> 1, wc = wid & 1;
    const int l15 = lane & 15, l4 = lane >> 4;

    const size_t aoff = (size_t)blockIdx.y * KT * 4096;   // ushort units
    const size_t boff = (size_t)blockIdx.x * KT * 4096;

    f32x4 acc[4][4];
#pragma unroll
    for (int i = 0; i < 4; i++)
#pragma unroll
        for (int j = 0; j < 4; j++) acc[i][j] = (f32x4){0.f, 0.f, 0.f, 0.f};

    short8 st[4][2];
    {   // preload K-step 0
        const size_t ab = aoff + tid * 8, bb = boff + tid * 8;
#pragma unroll
        for (int p = 0; p < 2; p++) {
            st[0][p] = *(const short8*)(Ahp + ab + p * 2048);
            st[1][p] = *(const short8*)(Alp + ab + p * 2048);
            st[2][p] = *(const short8*)(Bhp + bb + p * 2048);
            st[3][p] = *(const short8*)(Blp + bb + p * 2048);
        }
    }

    for (int t = 0; t < KT; t++) {
        __syncthreads();   // all reads of smem from step t-1 complete
#pragma unroll
        for (int pl = 0; pl < 4; pl++)
#pragma unroll
            for (int p = 0; p < 2; p++)
                *(short8*)&smem[pl][p * 2048 + tid * 8] = st[pl][p];

        if (t + 1 < KT) {  // prefetch next chunk (lands during MFMA phase)
            const size_t ab = aoff + (size_t)(t + 1) * 4096 + tid * 8;
            const size_t bb = boff + (size_t)(t + 1) * 4096 + tid * 8;
#pragma unroll
            for (int p = 0; p < 2; p++) {
                st[0][p] = *(const short8*)(Ahp + ab + p * 2048);
                st[1][p] = *(const short8*)(Alp + ab + p * 2048);
                st[2][p] = *(const short8*)(Bhp + bb + p * 2048);
                st[3][p] = *(const short8*)(Blp + bb + p * 2048);
            }
        }
        __syncthreads();   // staging visible

        short8 ahf[4], alf[4];
#pragma unroll
        for (int i = 0; i < 4; i++) {
            int m = wr * 64 + i * 16 + l15;
            int ks = (l4 << 3) ^ swz2(m);
            ahf[i] = *(const short8*)&smem[0][m * 32 + ks];
            alf[i] = *(const short8*)&smem[1][m * 32 + ks];
        }
#pragma unroll
        for (int j = 0; j < 4; j++) {
            int n = wc * 64 + j * 16 + l15;
            int ks = (l4 << 3) ^ swz2(n);
            short8 bhf = *(const short8*)&smem[2][n * 32 + ks];
            short8 blf = *(const short8*)&smem[3][n * 32 + ks];
#pragma unroll
            for (int i = 0; i < 4; i++) {
                acc[i][j] = __builtin_amdgcn_mfma_f32_16x16x32_bf16(ahf[i], bhf, acc[i][j], 0, 0, 0);
                acc[i][j] = __builtin_amdgcn_mfma_f32_16x16x32_bf16(ahf[i], blf, acc[i][j], 0, 0, 0);
                acc[i][j] = __builtin_amdgcn_mfma_f32_16x16x32_bf16(alf[i], bhf, acc[i][j], 0, 0, 0);
            }
        }
    }

    float* Cp = C + (size_t)(blockIdx.y * 128 + wr * 64 + (l4 << 2)) * Nn
                  + blockIdx.x * 128 + wc * 64 + l15;
#pragma unroll
    for (int i = 0; i < 4; i++) {
#pragma unroll
        for (int r = 0; r < 4; r++) {
            float* rowp = Cp + (size_t)(i * 16 + r) * Nn;
#pragma unroll
            for (int j = 0; j < 4; j++)
                rowp[j * 16] = acc[i][j][r];
        }
    }
}

// ---------------- fallback GEMM (round 3: in-loop conversion) ----------------

__global__ __launch_bounds__(256, 2) void k_gemm_mfma(const float* __restrict__ A,
                                                      const float* __restrict__ B,
                                                      float* __restrict__ C,
                                                      int M, int K, int Nn) {
    __shared__ unsigned short Ah[128][32];
    __shared__ unsigned short Al[128][32];
    __shared__ unsigned short Bh[128][32];   // [n][k] (transposed tile)
    __shared__ unsigned short Bl[128][32];

    const int tid = threadIdx.x;
    const int lane = tid & 63;
    const int wid = tid >> 6;
    const int wr = wid >> 1, wc = wid & 1;
    const int l15 = lane & 15, l4 = lane >> 4;

    const int a_r  = tid >> 1;
    const int a_k0 = (tid & 1) << 4;
    const int b_k  = tid >> 3;
    const int b_n0 = (tid & 7) << 4;

    const float* Ap = A + (size_t)(blockIdx.y * 128 + a_r) * K;
    const float* Bp = B + (size_t)blockIdx.x * 128 + b_n0;

    f32x4 acc[4][4];
#pragma unroll
    for (int i = 0; i < 4; i++)
#pragma unroll
        for (int j = 0; j < 4; j++) acc[i][j] = (f32x4){0.f, 0.f, 0.f, 0.f};

    const int nt = (K + 31) >> 5;
    const float4 z4 = make_float4(0.f, 0.f, 0.f, 0.f);

    float4 areg[4], breg[4];
    {
#pragma unroll
        for (int j = 0; j < 4; j++) {
            int k = a_k0 + (j << 2);
            areg[j] = (k < K) ? *(const float4*)(Ap + k) : z4;
        }
        bool bok = b_k < K;
#pragma unroll
        for (int j = 0; j < 4; j++)
            breg[j] = bok ? *(const float4*)(Bp + (size_t)b_k * Nn + (j << 2)) : z4;
    }

    for (int t = 0; t < nt; t++) {
        __syncthreads();
#pragma unroll
        for (int j = 0; j < 4; j++) {
            int kk = a_k0 + (j << 2);
            int ks = kk ^ swz(a_r);
            ushort4 h, l;
            split2(areg[j].x, h.x, l.x);
            split2(areg[j].y, h.y, l.y);
            split2(areg[j].z, h.z, l.z);
            split2(areg[j].w, h.w, l.w);
            *(ushort4*)&Ah[a_r][ks] = h;
            *(ushort4*)&Al[a_r][ks] = l;
        }
#pragma unroll
        for (int j = 0; j < 4; j++) {
            const float* bf = (const float*)&breg[j];
#pragma unroll
            for (int c = 0; c < 4; c++) {
                int n = b_n0 + (j << 2) + c;
                unsigned short h, l;
                split2(bf[c], h, l);
                int ks = b_k ^ swz(n);
                Bh[n][ks] = h;
                Bl[n][ks] = l;
            }
        }

        if (t + 1 < nt) {
            const int k0 = (t + 1) << 5;
#pragma unroll
            for (int j = 0; j < 4; j++) {
                int k = k0 + a_k0 + (j << 2);
                areg[j] = (k < K) ? *(const float4*)(Ap + k) : z4;
            }
            bool bok = (k0 + b_k) < K;
#pragma unroll
            for (int j = 0; j < 4; j++)
                breg[j] = bok ? *(const float4*)(Bp + (size_t)(k0 + b_k) * Nn + (j << 2)) : z4;
        }

        __syncthreads();

        short8 ahf[4], alf[4];
#pragma unroll
        for (int i = 0; i < 4; i++) {
            int m = wr * 64 + i * 16 + l15;
            int ks = (l4 << 3) ^ swz(m);
            ahf[i] = *(const short8*)&Ah[m][ks];
            alf[i] = *(const short8*)&Al[m][ks];
        }
#pragma unroll
        for (int j = 0; j < 4; j++) {
            int n = wc * 64 + j * 16 + l15;
            int ks = (l4 << 3) ^ swz(n);
            short8 bhf = *(const short8*)&Bh[n][ks];
            short8 blf = *(const short8*)&Bl[n][ks];
#pragma unroll
            for (int i = 0; i < 4; i++) {
                acc[i][j] = __builtin_amdgcn_mfma_f32_16x16x32_bf16(ahf[i], bhf, acc[i][j], 0, 0, 0);
                acc[i][j] = __builtin_amdgcn_mfma_f32_16x16x32_bf16(ahf[i], blf, acc[i][j], 0, 0, 0);
                acc[i][j] = __builtin_amdgcn_mfma_f32_16x16x32_bf16(alf[i], bhf, acc[i][j], 0, 0, 0);
            }
        }
    }

    float* Cp = C + (size_t)(blockIdx.y * 128 + wr * 64 + (l4 << 2)) * Nn
                  + blockIdx.x * 128 + wc * 64 + l15;
#pragma unroll
    for (int i = 0; i < 4; i++) {
#pragma unroll
        for (int r = 0; r < 4; r++) {
            float* rowp = Cp + (size_t)(i * 16 + r) * Nn;
#pragma unroll
            for (int j = 0; j < 4; j++)
                rowp[j * 16] = acc[i][j][r];
        }
    }
}

// ---------------- attention scores ----------------

__global__ __launch_bounds__(256) void k_scores(const float* __restrict__ h,
                                                const float* __restrict__ a_src,
                                                const float* __restrict__ a_dst,
                                                float* __restrict__ s_src,
                                                float* __restrict__ s_dst) {
    int wid = (blockIdx.x * 256 + threadIdx.x) >> 6;
    int lane = threadIdx.x & 63;
    if (wid >= NN * NH) return;
    int n = wid >> 4, hh = wid & 15;
    const float* hp = h + (size_t)n * FD + hh * HD;
    const float* as = a_src + hh * HD;
    const float* ad = a_dst + hh * HD;
    float ss = 0.f, sd = 0.f;
    for (int d = lane; d < HD; d += 64) {
        float v = hp[d];
        ss += v * as[d];
        sd += v * ad[d];
    }
#pragma unroll
    for (int o = 32; o > 0; o >>= 1) {
        ss += __shfl_xor(ss, o);
        sd += __shfl_xor(sd, o);
    }
    if (lane == 0) { s_src[wid] = ss; s_dst[wid] = sd; }
}

// ---------------- fused segment softmax + weighted gather ----------------

#define MAXCH 64

__global__ __launch_bounds__(256) void k_attn(const float* __restrict__ h,
                                              const float* __restrict__ s_src,
                                              const float* __restrict__ s_dst,
                                              const int* __restrict__ off,
                                              const int* __restrict__ csr,
                                              const float* __restrict__ bias,
                                              float* __restrict__ out) {
    const int t = blockIdx.x;
    const int tid = threadIdx.x;
    __shared__ float m_sh[NH], den_sh[NH];
    __shared__ float alpha[MAXCH][NH];
    __shared__ int src_sh[MAXCH];

    const int e0 = off[t], e1 = off[t + 1];

    if (tid < NH) {
        int hh = tid;
        float sd = s_dst[t * NH + hh];
        float m = -3.0e38f;
        for (int e = e0; e < e1; e++) {
            float v = s_src[csr[e] * NH + hh] + sd;
            v = v > 0.f ? v : SLOPE * v;
            m = fmaxf(m, v);
        }
        float den = 0.f;
        for (int e = e0; e < e1; e++) {
            float v = s_src[csr[e] * NH + hh] + sd;
            v = v > 0.f ? v : SLOPE * v;
            den += __expf(v - m);
        }
        m_sh[hh] = m;
        den_sh[hh] = den;
    }
    __syncthreads();

    float acc[32];
#pragma unroll
    for (int j = 0; j < 32; j++) acc[j] = 0.f;

    for (int c0 = e0; c0 < e1; c0 += MAXCH) {
        int ch = min(MAXCH, e1 - c0);
        for (int i = tid; i < ch * NH; i += 256) {
            int e = i >> 4, hh = i & 15;
            int s = csr[c0 + e];
            if (hh == 0) src_sh[e] = s;
            float v = s_src[s * NH + hh] + s_dst[t * NH + hh];
            v = v > 0.f ? v : SLOPE * v;
            alpha[e][hh] = __expf(v - m_sh[hh]) / den_sh[hh];
        }
        __syncthreads();
        for (int e = 0; e < ch; e++) {
            const float* hp = h + (size_t)src_sh[e] * FD;
#pragma unroll
            for (int j = 0; j < 32; j++)
                acc[j] += alpha[e][j >> 1] * hp[tid + (j << 8)];
        }
        __syncthreads();
    }

#pragma unroll
    for (int j = 0; j < 32; j++) {
        int f = tid + (j << 8);
        float v = acc[j] + bias[f];
        out[(size_t)t * FD + f] = v > 0.f ? v : 0.f;
    }
}

// ---------------- mean pool + head ----------------

__global__ __launch_bounds__(256) void k_pool(const float* __restrict__ h,
                                              const int* __restrict__ batch,
                                              float* __restrict__ pooled) {
    __shared__ int b_sh[NN];
    const int tid = threadIdx.x;
    const int f = blockIdx.x * 256 + tid;
    for (int i = tid; i < NN; i += 256) b_sh[i] = batch[i];
    __syncthreads();
    float acc[NG];
    int cnt[NG];
#pragma unroll
    for (int g = 0; g < NG; g++) { acc[g] = 0.f; cnt[g] = 0; }
    for (int n = 0; n < NN; n++) {
        int bg = b_sh[n];
        float v = h[(size_t)n * FD + f];
#pragma unroll
        for (int g = 0; g < NG; g++) {
            acc[g] += (bg == g) ? v : 0.f;
            cnt[g] += (bg == g) ? 1 : 0;
        }
    }
#pragma unroll
    for (int g = 0; g < NG; g++)
        pooled[(size_t)g * FD + f] = acc[g] / fmaxf((float)cnt[g], 1.f);
}

__global__ __launch_bounds__(256) void k_final(const float* __restrict__ pooled,
                                               const float* __restrict__ lin_w,
                                               const float* __restrict__ lin_b,
                                               float* __restrict__ outv) {
    const int g = blockIdx.x;
    const int tid = threadIdx.x;
    float s = 0.f;
    for (int f = tid; f < FD; f += 256)
        s += pooled[(size_t)g * FD + f] * lin_w[f];
    __shared__ float red[256];
    red[tid] = s;
    __syncthreads();
    for (int o = 128; o > 0; o >>= 1) {
        if (tid < o) red[tid] += red[tid + o];
        __syncthreads();
    }
    if (tid == 0) outv[g] = red[0] + lin_b[0];
}

// ---------------- launch ----------------

extern "C" void kernel_launch(void* const* d_in, const int* in_sizes, int n_in,
                              void* d_out, int out_size, void* d_ws, size_t ws_size,
                              hipStream_t stream) {
    const float* x   = (const float*)d_in[0];
    const int*   ei  = (const int*)d_in[1];
    const int*   bat = (const int*)d_in[2];
    const float* W1  = (const float*)d_in[3];
    const float* as1 = (const float*)d_in[4];
    const float* ad1 = (const float*)d_in[5];
    const float* b1  = (const float*)d_in[6];
    const float* W2  = (const float*)d_in[7];
    const float* as2 = (const float*)d_in[8];
    const float* ad2 = (const float*)d_in[9];
    const float* b2  = (const float*)d_in[10];
    const float* lw  = (const float*)d_in[11];
    const float* lb  = (const float*)d_in[12];

    char* p0 = (char*)d_ws;
    char* p = p0;
    auto alloc = [&](size_t bytes) {
        char* r = p;
        p += (bytes + 255) & ~size_t(255);
        return r;
    };
    int* counts   = (int*)alloc((NN + 1) * sizeof(int));
    int* off      = (int*)alloc((NN + 1) * sizeof(int));
    int* cursor   = (int*)alloc(NN * sizeof(int));
    int* csr      = (int*)alloc(ET * sizeof(int));
    float* ssrc   = (float*)alloc((size_t)NN * NH * sizeof(float));
    float* sdst   = (float*)alloc((size_t)NN * NH * sizeof(float));
    float* hbuf   = (float*)alloc((size_t)NN * FD * sizeof(float));
    float* abuf   = (float*)alloc((size_t)NN * FD * sizeof(float));
    float* pooled = (float*)alloc((size_t)NG * FD * sizeof(float));

    // plane buffers (bf16 hi/lo, chunk-image layout)
    const int KT1 = (IN_DIM + 31) / 32;   // 41
    const int KT2 = FD / 32;              // 256
    const size_t sz_xp  = (size_t)(NN / 128) * KT1 * 4096;   // ushorts
    const size_t sz_w1p = (size_t)(FD / 128) * KT1 * 4096;
    const size_t sz_w2p = (size_t)(FD / 128) * KT2 * 4096;
    const size_t sz_h2p = (size_t)(NN / 128) * KT2 * 4096;
    unsigned short* xH  = (unsigned short*)alloc(sz_xp * 2);
    unsigned short* xL  = (unsigned short*)alloc(sz_xp * 2);
    unsigned short* w1H = (unsigned short*)alloc(sz_w1p * 2);
    unsigned short* w1L = (unsigned short*)alloc(sz_w1p * 2);
    unsigned short* w2H = (unsigned short*)alloc(sz_w2p * 2);
    unsigned short* w2L = (unsigned short*)alloc(sz_w2p * 2);
    unsigned short* h2H = (unsigned short*)alloc(sz_h2p * 2);
    unsigned short* h2L = (unsigned short*)alloc(sz_h2p * 2);
    const bool planes_ok = (size_t)(p - p0) <= ws_size;   // constant per session

    const int* esrc = ei;        // edge_index[0]
    const int* edst = ei + EE;   // edge_index[1]

    // CSR by dst (self loops appended)
    k_init_counts<<<(NN + 255) / 256, 256, 0, stream>>>(counts);
    k_count<<<(EE + 255) / 256, 256, 0, stream>>>(edst, counts);
    k_scan<<<1, NN, 0, stream>>>(counts, off, cursor);
    k_fill<<<(ET + 255) / 256, 256, 0, stream>>>(esrc, edst, off, cursor, csr);

    // grid: x = n-tile (fast) -> the 8 m-tiles sharing a B panel are 64 apart
    // in linear id -> same XCD under %8 round-robin; B panel ~4MB fits XCD L2.
    dim3 gg(FD / 128, NN / 128);

    // layer 1
    if (planes_ok) {
        k_conv_a<<<(NN / 128) * KT1, 256, 0, stream>>>(x, xH, xL, IN_DIM, KT1);
        k_conv_b<<<(FD / 128) * KT1, 256, 0, stream>>>(W1, w1H, w1L, IN_DIM, FD, KT1);
        k_conv_b<<<(FD / 128) * KT2, 256, 0, stream>>>(W2, w2H, w2L, FD, FD, KT2);
        k_gemm_planes<<<gg, 256, 0, stream>>>(xH, xL, w1H, w1L, hbuf, KT1, FD);
    } else {
        k_gemm_mfma<<<gg, 256, 0, stream>>>(x, W1, hbuf, NN, IN_DIM, FD);
    }
    k_scores<<<NN * NH / 4, 256, 0, stream>>>(hbuf, as1, ad1, ssrc, sdst);
    k_attn<<<NN, 256, 0, stream>>>(hbuf, ssrc, sdst, off, csr, b1, abuf);

    // layer 2
    if (planes_ok) {
        k_conv_a<<<(NN / 128) * KT2, 256, 0, stream>>>(abuf, h2H, h2L, FD, KT2);
        k_gemm_planes<<<gg, 256, 0, stream>>>(h2H, h2L, w2H, w2L, hbuf, KT2, FD);
    } else {
        k_gemm_mfma<<<gg, 256, 0, stream>>>(abuf, W2, hbuf, NN, FD, FD);
    }
    k_scores<<<NN * NH / 4, 256, 0, stream>>>(hbuf, as2, ad2, ssrc, sdst);
    k_attn<<<NN, 256, 0, stream>>>(hbuf, ssrc, sdst, off, csr, b2, abuf);

    // pool + head
    k_pool<<<FD / 256, 256, 0, stream>>>(abuf, bat, pooled);
    k_final<<<NG, 256, 0, stream>>>(pooled, lw, lb, (float*)d_out);
}

// Round 6
// 1376.639 us; speedup vs baseline: 1.0127x; 1.0127x over previous
//
#include <hip/hip_runtime.h>

// GATClassifier: 2x GATConv(H=16, D=512) + ReLU, mean-pool per graph, linear head.
// N=1024, E=16384 (+N self loops), IN=1300, F=H*D=8192, G=8.
// Round 6: plane-GEMM rescheduled with global_load_lds + double-buffer LDS +
// counted vmcnt(8) across raw s_barriers (T3/T4 pattern; planes are pre-swizzled
// chunk images -> linear LDS dest is legal). Attn-as-GEMM tier from round 5.
// Measured round 4: GEMM2 422us MfmaUtil 45%, 0 bank conflicts -> barrier-drain
// bound; this schedule attacks that stall.

#define NN      1024
#define EE      16384
#define IN_DIM  1300
#define NH      16
#define HD      512
#define FD      8192       // NH*HD
#define NG      8
#define ET      (EE + NN)  // edges incl. self loops
#define SLOPE   0.2f

typedef __attribute__((ext_vector_type(8))) short short8;
typedef __attribute__((ext_vector_type(4))) float f32x4;

// ---------------- CSR build (counting sort by dst) ----------------

__global__ void k_init_counts(int* counts) {
    int i = blockIdx.x * 256 + threadIdx.x;
    if (i < NN) counts[i] = 1;              // self-loop contributes 1
}

__global__ void k_count(const int* __restrict__ dst, int* counts) {
    int e = blockIdx.x * 256 + threadIdx.x;
    if (e < EE) atomicAdd(&counts[dst[e]], 1);
}

__global__ void k_scan(const int* __restrict__ counts, int* __restrict__ off,
                       int* __restrict__ cursor) {
    __shared__ int s[NN];
    int t = threadIdx.x;
    s[t] = counts[t];
    __syncthreads();
    for (int d = 1; d < NN; d <<= 1) {
        int v = (t >= d) ? s[t - d] : 0;
        __syncthreads();
        s[t] += v;
        __syncthreads();
    }
    off[t + 1] = s[t];
    if (t == 0) off[0] = 0;
    cursor[t] = 0;
}

__global__ void k_fill2(const int* __restrict__ srcv, const int* __restrict__ dstv,
                        const int* __restrict__ off, int* cursor,
                        int* __restrict__ csr, int* __restrict__ csr_dst) {
    int e = blockIdx.x * 256 + threadIdx.x;
    if (e < EE) {
        int d = dstv[e];
        int p = atomicAdd(&cursor[d], 1);
        csr[off[d] + p] = srcv[e];
        csr_dst[off[d] + p] = d;
    } else if (e < ET) {
        int n = e - EE;                      // self loop (n,n)
        int p = atomicAdd(&cursor[n], 1);
        csr[off[n] + p] = n;
        csr_dst[off[n] + p] = n;
    }
}

__global__ void k_fill(const int* __restrict__ srcv, const int* __restrict__ dstv,
                       const int* __restrict__ off, int* cursor, int* __restrict__ csr) {
    int e = blockIdx.x * 256 + threadIdx.x;
    if (e < EE) {
        int d = dstv[e];
        int p = atomicAdd(&cursor[d], 1);
        csr[off[d] + p] = srcv[e];
    } else if (e < ET) {
        int n = e - EE;
        int p = atomicAdd(&cursor[n], 1);
        csr[off[n] + p] = n;
    }
}

// ---------------- bf16 split helpers + swizzles ----------------

__device__ __forceinline__ int swz2(int r) {
    return (((r >> 1) & 3) ^ ((r >> 4) & 3)) << 3;
}
__device__ __forceinline__ int swz(int r) {
    return ((r & 3) ^ ((r >> 4) & 3)) << 3;
}

__device__ __forceinline__ unsigned short bf16_rne(float f) {
    unsigned int u = __float_as_uint(f);
    u += 0x7FFF + ((u >> 16) & 1);
    return (unsigned short)(u >> 16);
}

__device__ __forceinline__ void split2(float f, unsigned short& h, unsigned short& l) {
    unsigned short hh = bf16_rne(f);
    float hf = __uint_as_float(((unsigned int)hh) << 16);
    h = hh;
    l = bf16_rne(f - hf);
}

__device__ __forceinline__ void gload16(const void* g, void* l) {
    __builtin_amdgcn_global_load_lds((const __attribute__((address_space(1))) void*)g,
                                     (__attribute__((address_space(3))) void*)l,
                                     16, 0, 0);
}

// ---------------- plane conversion kernels ----------------
// Chunk = LDS image of one 128x32 tile of one plane: ushort L[128][32],
//   A-style: L[r][kc] = val(row0+r, k0 + (kc ^ swz2(r)))      (rows = M)
//   B-style: L[n][kc] = val(k0 + (kc ^ swz2(n)), col0+n)      (rows = N, transposed)
// Chunks ordered [row_tile][k_tile]; k >= K zero-padded.

__global__ __launch_bounds__(256) void k_conv_a(const float* __restrict__ S,
                                                unsigned short* __restrict__ H,
                                                unsigned short* __restrict__ L,
                                                int K, int KT) {
    const int chunk = blockIdx.x;                 // mt*KT + kt
    const int mt = chunk / KT, kt = chunk - mt * KT;
    const int tid = threadIdx.x;
    const size_t ob = (size_t)chunk * 4096;
#pragma unroll
    for (int half = 0; half < 2; half++) {
        const int r = (tid >> 2) + half * 64;
        const int kc0 = (tid & 3) << 3;
        const int k = kt * 32 + (kc0 ^ swz2(r));  // multiple of 8
        const float* src = S + (size_t)(mt * 128 + r) * K + k;
        float4 f0 = make_float4(0.f, 0.f, 0.f, 0.f), f1 = f0;
        if (k < K)     f0 = *(const float4*)src;        // K%4==0 -> exact
        if (k + 4 < K) f1 = *(const float4*)(src + 4);
        float vals[8] = {f0.x, f0.y, f0.z, f0.w, f1.x, f1.y, f1.z, f1.w};
        short8 hv, lv;
#pragma unroll
        for (int j = 0; j < 8; j++) {
            unsigned short h, l;
            split2(vals[j], h, l);
            hv[j] = (short)h;
            lv[j] = (short)l;
        }
        *(short8*)(H + ob + r * 32 + kc0) = hv;
        *(short8*)(L + ob + r * 32 + kc0) = lv;
    }
}

__global__ __launch_bounds__(256) void k_conv_b(const float* __restrict__ S,
                                                unsigned short* __restrict__ H,
                                                unsigned short* __restrict__ L,
                                                int K, int Nn, int KT) {
    __shared__ float T[128][33];                  // transposed fp32 tile
    const int chunk = blockIdx.x;                 // nt*KT + kt
    const int nt = chunk / KT, kt = chunk - nt * KT;
    const int tid = threadIdx.x;
    {
        const int kr = tid >> 3;                  // 0..31
        const int c0 = (tid & 7) << 4;            // 0..112
        const int k = kt * 32 + kr;
        const float* row = S + (size_t)k * Nn + nt * 128 + c0;
#pragma unroll
        for (int j = 0; j < 4; j++) {
            float4 v = (k < K) ? *(const float4*)(row + (j << 2))
                               : make_float4(0.f, 0.f, 0.f, 0.f);
            T[c0 + (j << 2) + 0][kr] = v.x;
            T[c0 + (j << 2) + 1][kr] = v.y;
            T[c0 + (j << 2) + 2][kr] = v.z;
            T[c0 + (j << 2) + 3][kr] = v.w;
        }
    }
    __syncthreads();
    const size_t ob = (size_t)chunk * 4096;
#pragma unroll
    for (int half = 0; half < 2; half++) {
        const int n = (tid >> 2) + half * 64;
        const int kc0 = (tid & 3) << 3;
        const int ks = kc0 ^ swz2(n);             // contiguous 8 in T row
        short8 hv, lv;
#pragma unroll
        for (int j = 0; j < 8; j++) {
            unsigned short h, l;
            split2(T[n][ks + j], h, l);
            hv[j] = (short)h;
            lv[j] = (short)l;
        }
        *(short8*)(H + ob + n * 32 + kc0) = hv;
        *(short8*)(L + ob + n * 32 + kc0) = lv;
    }
}

// P-planes conversion: Pf [head][1024][1024] fp32 -> A-chunks [head][mt=8][kt=32]
__global__ __launch_bounds__(256) void k_conv_pa(const float* __restrict__ Pf,
                                                 unsigned short* __restrict__ H,
                                                 unsigned short* __restrict__ L) {
    const int chunk = blockIdx.x;                 // head*256 + mt*32 + kt
    const int head = chunk >> 8;
    const int rem = chunk & 255;
    const int mt = rem >> 5, kt = rem & 31;
    const int tid = threadIdx.x;
    const size_t ob = (size_t)chunk * 4096;
    const float* base = Pf + (size_t)head * NN * NN;
#pragma unroll
    for (int half = 0; half < 2; half++) {
        const int r = (tid >> 2) + half * 64;
        const int kc0 = (tid & 3) << 3;
        const int k = kt * 32 + (kc0 ^ swz2(r));
        const float* src = base + (size_t)(mt * 128 + r) * NN + k;
        float4 f0 = *(const float4*)src;
        float4 f1 = *(const float4*)(src + 4);
        float vals[8] = {f0.x, f0.y, f0.z, f0.w, f1.x, f1.y, f1.z, f1.w};
        short8 hv, lv;
#pragma unroll
        for (int j = 0; j < 8; j++) {
            unsigned short h, l;
            split2(vals[j], h, l);
            hv[j] = (short)h;
            lv[j] = (short)l;
        }
        *(short8*)(H + ob + r * 32 + kc0) = hv;
        *(short8*)(L + ob + r * 32 + kc0) = lv;
    }
}

// ---------------- softmax stats + P scatter ----------------

__global__ __launch_bounds__(256) void k_stats(const float* __restrict__ ssrc,
                                               const float* __restrict__ sdstv,
                                               const int* __restrict__ off,
                                               const int* __restrict__ csr,
                                               float* __restrict__ md,
                                               float* __restrict__ dn) {
    const int t = blockIdx.x;
    const int i = threadIdx.x;
    const int head = i >> 4, sub = i & 15;
    const int e0 = off[t], e1 = off[t + 1];
    const float sd = sdstv[t * NH + head];
    float m = -3.0e38f;
    for (int e = e0 + sub; e < e1; e += 16) {
        float v = ssrc[csr[e] * NH + head] + sd;
        v = v > 0.f ? v : SLOPE * v;
        m = fmaxf(m, v);
    }
#pragma unroll
    for (int o = 8; o > 0; o >>= 1) m = fmaxf(m, __shfl_xor(m, o));
    float den = 0.f;
    for (int e = e0 + sub; e < e1; e += 16) {
        float v = ssrc[csr[e] * NH + head] + sd;
        v = v > 0.f ? v : SLOPE * v;
        den += __expf(v - m);
    }
#pragma unroll
    for (int o = 8; o > 0; o >>= 1) den += __shfl_xor(den, o);
    if (sub == 0) { md[t * NH + head] = m; dn[t * NH + head] = den; }
}

__global__ void k_zero4(float4* __restrict__ p, int n4) {
    int i = blockIdx.x * 256 + threadIdx.x;
    const int stride = gridDim.x * 256;
    const float4 z = make_float4(0.f, 0.f, 0.f, 0.f);
    for (; i < n4; i += stride) p[i] = z;
}

// one thread per edge, loops heads; atomicAdd handles duplicate (s,t) edges
// (duplicates add IDENTICAL alpha -> order-independent sum).
__global__ __launch_bounds__(256) void k_scatter(const int* __restrict__ csr,
                                                 const int* __restrict__ csr_dst,
                                                 const float* __restrict__ ssrc,
                                                 const float* __restrict__ sdstv,
                                                 const float* __restrict__ md,
                                                 const float* __restrict__ dn,
                                                 float* __restrict__ Pf) {
    const int e = blockIdx.x * 256 + threadIdx.x;
    if (e >= ET) return;
    const int s = csr[e], t = csr_dst[e];
#pragma unroll
    for (int hh = 0; hh < NH; hh++) {
        float v = ssrc[s * NH + hh] + sdstv[t * NH + hh];
        v = v > 0.f ? v : SLOPE * v;
        float a = __expf(v - md[t * NH + hh]) / dn[t * NH + hh];
        atomicAdd(&Pf[(size_t)hh * NN * NN + (size_t)t * NN + s], a);
    }
}

// ---------------- plane-path GEMM (counted-vmcnt schedule) ----------------
// headed=0: C[M][Nn] = A@B, A-chunks [mt=by][kt], grid(Nn/128, M/128)
// headed=1: per-head attn GEMM, A-chunks [head=bx>>2][mt=by][kt], grid(64, 8)
// bias (nullable, per output col) + optional ReLU fused in epilogue.
// Staging: global_load_lds width=16 into double-buffered linear LDS (planes are
// pre-swizzled chunk images). Per K-step: lgkmcnt(0); s_barrier; issue 8 loads
// for t+2 into just-read buffer; s_waitcnt vmcnt(8) (t+1 landed, t+2 in flight);
// s_barrier. vmcnt never drains to 0 in the main loop (T4). Requires KT >= 3.

__global__ __launch_bounds__(256, 2) void k_gemm_planes(
        const unsigned short* __restrict__ Ahp, const unsigned short* __restrict__ Alp,
        const unsigned short* __restrict__ Bhp, const unsigned short* __restrict__ Blp,
        float* __restrict__ C, int KT, int Nn,
        const float* __restrict__ bias, int relu, int headed) {
    __shared__ short smem[2][4][4096];            // [buf][plane][chunk image] 64 KB
    const int tid = threadIdx.x;
    const int lane = tid & 63;
    const int wid = tid >> 6;
    const int wr = wid >> 1, wc = wid & 1;
    const int l15 = lane & 15, l4 = lane >> 4;

    const size_t amt = headed ? ((size_t)(blockIdx.x >> 2) * 8 + blockIdx.y)
                              : (size_t)blockIdx.y;
    const size_t aoff = amt * KT * 4096;          // ushort units
    const size_t boff = (size_t)blockIdx.x * KT * 4096;

    f32x4 acc[4][4];
#pragma unroll
    for (int i = 0; i < 4; i++)
#pragma unroll
        for (int j = 0; j < 4; j++) acc[i][j] = (f32x4){0.f, 0.f, 0.f, 0.f};

    // per-thread global offset within a chunk: wave*512 + lane*8 shorts (+q*2048)
    const int thg = (wid << 9) + (lane << 3);
    const int ldw = (wid << 9);                   // wave-uniform LDS part

    auto STAGE = [&](int b, int t2) {
        const size_t ca = aoff + (size_t)t2 * 4096;
        const size_t cb = boff + (size_t)t2 * 4096;
#pragma unroll
        for (int q = 0; q < 2; q++) {
            const int so = (q << 11) + thg;
            const int lo = (q << 11) + ldw;
            gload16(Ahp + ca + so, &smem[b][0][lo]);
            gload16(Alp + ca + so, &smem[b][1][lo]);
            gload16(Bhp + cb + so, &smem[b][2][lo]);
            gload16(Blp + cb + so, &smem[b][3][lo]);
        }
    };

    // prologue: prefetch tiles 0 and 1 (depth 2)
    STAGE(0, 0);
    STAGE(1, 1);
    asm volatile("s_waitcnt vmcnt(8)" ::: "memory");   // tile 0 landed
    __builtin_amdgcn_sched_barrier(0);
    __builtin_amdgcn_s_barrier();

    int cur = 0;
    for (int t = 0; t < KT; ++t) {
        // ---- compute on buf[cur] (compiler interleaves ds_read_b128 + MFMA) ----
        short8 ahf[4], alf[4];
#pragma unroll
        for (int i = 0; i < 4; i++) {
            int m = wr * 64 + i * 16 + l15;
            int ks = (l4 << 3) ^ swz2(m);
            ahf[i] = *(const short8*)&smem[cur][0][m * 32 + ks];
            alf[i] = *(const short8*)&smem[cur][1][m * 32 + ks];
        }
#pragma unroll
        for (int j = 0; j < 4; j++) {
            int n = wc * 64 + j * 16 + l15;
            int ks = (l4 << 3) ^ swz2(n);
            short8 bhf = *(const short8*)&smem[cur][2][n * 32 + ks];
            short8 blf = *(const short8*)&smem[cur][3][n * 32 + ks];
#pragma unroll
            for (int i = 0; i < 4; i++) {
                acc[i][j] = __builtin_amdgcn_mfma_f32_16x16x32_bf16(ahf[i], bhf, acc[i][j], 0, 0, 0);
                acc[i][j] = __builtin_amdgcn_mfma_f32_16x16x32_bf16(ahf[i], blf, acc[i][j], 0, 0, 0);
                acc[i][j] = __builtin_amdgcn_mfma_f32_16x16x32_bf16(alf[i], bhf, acc[i][j], 0, 0, 0);
            }
        }

        if (t + 1 < KT) {
            // all our LDS reads of buf[cur] retired
            asm volatile("s_waitcnt lgkmcnt(0)" ::: "memory");
            __builtin_amdgcn_sched_barrier(0);
            __builtin_amdgcn_s_barrier();          // all waves done with buf[cur]
            __builtin_amdgcn_sched_barrier(0);
            if (t + 2 < KT) {
                STAGE(cur, t + 2);                 // overwrite just-read buffer
                asm volatile("s_waitcnt vmcnt(8)" ::: "memory");  // t+1 landed
            } else {
                asm volatile("s_waitcnt vmcnt(0)" ::: "memory");  // drain t+1
            }
            __builtin_amdgcn_sched_barrier(0);
            __builtin_amdgcn_s_barrier();          // buf[cur^1] valid for all
            cur ^= 1;
        }
    }

    const int col0 = blockIdx.x * 128 + wc * 64 + l15;
    float bj[4];
#pragma unroll
    for (int j = 0; j < 4; j++) bj[j] = bias ? bias[col0 + j * 16] : 0.f;

    float* Cp = C + (size_t)(blockIdx.y * 128 + wr * 64 + (l4 << 2)) * Nn + col0;
#pragma unroll
    for (int i = 0; i < 4; i++) {
#pragma unroll
        for (int r = 0; r < 4; r++) {
            float* rowp = Cp + (size_t)(i * 16 + r) * Nn;
#pragma unroll
            for (int j = 0; j < 4; j++) {
                float v = acc[i][j][r] + bj[j];
                if (relu) v = fmaxf(v, 0.f);
                rowp[j * 16] = v;
            }
        }
    }
}

// ---------------- fallback GEMM (in-loop conversion; tier C) ----------------

__global__ __launch_bounds__(256, 2) void k_gemm_mfma(const float* __restrict__ A,
                                                      const float* __restrict__ B,
                                                      float* __restrict__ C,
                                                      int M, int K, int Nn) {
    __shared__ unsigned short Ah[128][32];
    __shared__ unsigned short Al[128][32];
    __shared__ unsigned short Bh[128][32];
    __shared__ unsigned short Bl[128][32];

    const int tid = threadIdx.x;
    const int lane = tid & 63;
    const int wid = tid >> 6;
    const int wr = wid >> 1, wc = wid & 1;
    const int l15 = lane & 15, l4 = lane >> 4;

    const int a_r  = tid >> 1;
    const int a_k0 = (tid & 1) << 4;
    const int b_k  = tid >> 3;
    const int b_n0 = (tid & 7) << 4;

    const float* Ap = A + (size_t)(blockIdx.y * 128 + a_r) * K;
    const float* Bp = B + (size_t)blockIdx.x * 128 + b_n0;

    f32x4 acc[4][4];
#pragma unroll
    for (int i = 0; i < 4; i++)
#pragma unroll
        for (int j = 0; j < 4; j++) acc[i][j] = (f32x4){0.f, 0.f, 0.f, 0.f};

    const int nt = (K + 31) >> 5;
    const float4 z4 = make_float4(0.f, 0.f, 0.f, 0.f);

    float4 areg[4], breg[4];
    {
#pragma unroll
        for (int j = 0; j < 4; j++) {
            int k = a_k0 + (j << 2);
            areg[j] = (k < K) ? *(const float4*)(Ap + k) : z4;
        }
        bool bok = b_k < K;
#pragma unroll
        for (int j = 0; j < 4; j++)
            breg[j] = bok ? *(const float4*)(Bp + (size_t)b_k * Nn + (j << 2)) : z4;
    }

    for (int t = 0; t < nt; t++) {
        __syncthreads();
#pragma unroll
        for (int j = 0; j < 4; j++) {
            int kk = a_k0 + (j << 2);
            int ks = kk ^ swz(a_r);
            ushort4 h, l;
            split2(areg[j].x, h.x, l.x);
            split2(areg[j].y, h.y, l.y);
            split2(areg[j].z, h.z, l.z);
            split2(areg[j].w, h.w, l.w);
            *(ushort4*)&Ah[a_r][ks] = h;
            *(ushort4*)&Al[a_r][ks] = l;
        }
#pragma unroll
        for (int j = 0; j < 4; j++) {
            const float* bf = (const float*)&breg[j];
#pragma unroll
            for (int c = 0; c < 4; c++) {
                int n = b_n0 + (j << 2) + c;
                unsigned short h, l;
                split2(bf[c], h, l);
                int ks = b_k ^ swz(n);
                Bh[n][ks] = h;
                Bl[n][ks] = l;
            }
        }

        if (t + 1 < nt) {
            const int k0 = (t + 1) << 5;
#pragma unroll
            for (int j = 0; j < 4; j++) {
                int k = k0 + a_k0 + (j << 2);
                areg[j] = (k < K) ? *(const float4*)(Ap + k) : z4;
            }
            bool bok = (k0 + b_k) < K;
#pragma unroll
            for (int j = 0; j < 4; j++)
                breg[j] = bok ? *(const float4*)(Bp + (size_t)(k0 + b_k) * Nn + (j << 2)) : z4;
        }

        __syncthreads();

        short8 ahf[4], alf[4];
#pragma unroll
        for (int i = 0; i < 4; i++) {
            int m = wr * 64 + i * 16 + l15;
            int ks = (l4 << 3) ^ swz(m);
            ahf[i] = *(const short8*)&Ah[m][ks];
            alf[i] = *(const short8*)&Al[m][ks];
        }
#pragma unroll
        for (int j = 0; j < 4; j++) {
            int n = wc * 64 + j * 16 + l15;
            int ks = (l4 << 3) ^ swz(n);
            short8 bhf = *(const short8*)&Bh[n][ks];
            short8 blf = *(const short8*)&Bl[n][ks];
#pragma unroll
            for (int i = 0; i < 4; i++) {
                acc[i][j] = __builtin_amdgcn_mfma_f32_16x16x32_bf16(ahf[i], bhf, acc[i][j], 0, 0, 0);
                acc[i][j] = __builtin_amdgcn_mfma_f32_16x16x32_bf16(ahf[i], blf, acc[i][j], 0, 0, 0);
                acc[i][j] = __builtin_amdgcn_mfma_f32_16x16x32_bf16(alf[i], bhf, acc[i][j], 0, 0, 0);
            }
        }
    }

    float* Cp = C + (size_t)(blockIdx.y * 128 + wr * 64 + (l4 << 2)) * Nn
                  + blockIdx.x * 128 + wc * 64 + l15;
#pragma unroll
    for (int i = 0; i < 4; i++) {
#pragma unroll
        for (int r = 0; r < 4; r++) {
            float* rowp = Cp + (size_t)(i * 16 + r) * Nn;
#pragma unroll
            for (int j = 0; j < 4; j++)
                rowp[j * 16] = acc[i][j][r];
        }
    }
}

// ---------------- attention scores ----------------

__global__ __launch_bounds__(256) void k_scores(const float* __restrict__ h,
                                                const float* __restrict__ a_src,
                                                const float* __restrict__ a_dst,
                                                float* __restrict__ s_src,
                                                float* __restrict__ s_dst) {
    int wid = (blockIdx.x * 256 + threadIdx.x) >> 6;
    int lane = threadIdx.x & 63;
    if (wid >= NN * NH) return;
    int n = wid >> 4, hh = wid & 15;
    const float* hp = h + (size_t)n * FD + hh * HD;
    const float* as = a_src + hh * HD;
    const float* ad = a_dst + hh * HD;
    float ss = 0.f, sd = 0.f;
    for (int d = lane; d < HD; d += 64) {
        float v = hp[d];
        ss += v * as[d];
        sd += v * ad[d];
    }
#pragma unroll
    for (int o = 32; o > 0; o >>= 1) {
        ss += __shfl_xor(ss, o);
        sd += __shfl_xor(sd, o);
    }
    if (lane == 0) { s_src[wid] = ss; s_dst[wid] = sd; }
}

// ---------------- fallback fused attn (tier B/C) ----------------

#define MAXCH 64

__global__ __launch_bounds__(256) void k_attn(const float* __restrict__ h,
                                              const float* __restrict__ s_src,
                                              const float* __restrict__ s_dst,
                                              const int* __restrict__ off,
                                              const int* __restrict__ csr,
                                              const float* __restrict__ bias,
                                              float* __restrict__ out) {
    const int t = blockIdx.x;
    const int tid = threadIdx.x;
    __shared__ float m_sh[NH], den_sh[NH];
    __shared__ float alpha[MAXCH][NH];
    __shared__ int src_sh[MAXCH];

    const int e0 = off[t], e1 = off[t + 1];

    if (tid < NH) {
        int hh = tid;
        float sd = s_dst[t * NH + hh];
        float m = -3.0e38f;
        for (int e = e0; e < e1; e++) {
            float v = s_src[csr[e] * NH + hh] + sd;
            v = v > 0.f ? v : SLOPE * v;
            m = fmaxf(m, v);
        }
        float den = 0.f;
        for (int e = e0; e < e1; e++) {
            float v = s_src[csr[e] * NH + hh] + sd;
            v = v > 0.f ? v : SLOPE * v;
            den += __expf(v - m);
        }
        m_sh[hh] = m;
        den_sh[hh] = den;
    }
    __syncthreads();

    float acc[32];
#pragma unroll
    for (int j = 0; j < 32; j++) acc[j] = 0.f;

    for (int c0 = e0; c0 < e1; c0 += MAXCH) {
        int ch = min(MAXCH, e1 - c0);
        for (int i = tid; i < ch * NH; i += 256) {
            int e = i >> 4, hh = i & 15;
            int s = csr[c0 + e];
            if (hh == 0) src_sh[e] = s;
            float v = s_src[s * NH + hh] + s_dst[t * NH + hh];
            v = v > 0.f ? v : SLOPE * v;
            alpha[e][hh] = __expf(v - m_sh[hh]) / den_sh[hh];
        }
        __syncthreads();
        for (int e = 0; e < ch; e++) {
            const float* hp = h + (size_t)src_sh[e] * FD;
#pragma unroll
            for (int j = 0; j < 32; j++)
                acc[j] += alpha[e][j >> 1] * hp[tid + (j << 8)];
        }
        __syncthreads();
    }

#pragma unroll
    for (int j = 0; j < 32; j++) {
        int f = tid + (j << 8);
        float v = acc[j] + bias[f];
        out[(size_t)t * FD + f] = v > 0.f ? v : 0.f;
    }
}

// ---------------- mean pool + head ----------------

__global__ __launch_bounds__(256) void k_pool(const float* __restrict__ h,
                                              const int* __restrict__ batch,
                                              float* __restrict__ pooled) {
    __shared__ int b_sh[NN];
    const int tid = threadIdx.x;
    const int f = blockIdx.x * 256 + tid;
    for (int i = tid; i < NN; i += 256) b_sh[i] = batch[i];
    __syncthreads();
    float acc[NG];
    int cnt[NG];
#pragma unroll
    for (int g = 0; g < NG; g++) { acc[g] = 0.f; cnt[g] = 0; }
    for (int n = 0; n < NN; n++) {
        int bg = b_sh[n];
        float v = h[(size_t)n * FD + f];
#pragma unroll
        for (int g = 0; g < NG; g++) {
            acc[g] += (bg == g) ? v : 0.f;
            cnt[g] += (bg == g) ? 1 : 0;
        }
    }
#pragma unroll
    for (int g = 0; g < NG; g++)
        pooled[(size_t)g * FD + f] = acc[g] / fmaxf((float)cnt[g], 1.f);
}

__global__ __launch_bounds__(256) void k_final(const float* __restrict__ pooled,
                                               const float* __restrict__ lin_w,
                                               const float* __restrict__ lin_b,
                                               float* __restrict__ outv) {
    const int g = blockIdx.x;
    const int tid = threadIdx.x;
    float s = 0.f;
    for (int f = tid; f < FD; f += 256)
        s += pooled[(size_t)g * FD + f] * lin_w[f];
    __shared__ float red[256];
    red[tid] = s;
    __syncthreads();
    for (int o = 128; o > 0; o >>= 1) {
        if (tid < o) red[tid] += red[tid + o];
        __syncthreads();
    }
    if (tid == 0) outv[g] = red[0] + lin_b[0];
}

// ---------------- launch ----------------

extern "C" void kernel_launch(void* const* d_in, const int* in_sizes, int n_in,
                              void* d_out, int out_size, void* d_ws, size_t ws_size,
                              hipStream_t stream) {
    const float* x   = (const float*)d_in[0];
    const int*   ei  = (const int*)d_in[1];
    const int*   bat = (const int*)d_in[2];
    const float* W1  = (const float*)d_in[3];
    const float* as1 = (const float*)d_in[4];
    const float* ad1 = (const float*)d_in[5];
    const float* b1  = (const float*)d_in[6];
    const float* W2  = (const float*)d_in[7];
    const float* as2 = (const float*)d_in[8];
    const float* ad2 = (const float*)d_in[9];
    const float* b2  = (const float*)d_in[10];
    const float* lw  = (const float*)d_in[11];
    const float* lb  = (const float*)d_in[12];

    char* p0 = (char*)d_ws;
    char* p = p0;
    auto alloc = [&](size_t bytes) {
        char* r = p;
        p += (bytes + 255) & ~size_t(255);
        return r;
    };
    int* counts   = (int*)alloc((NN + 1) * sizeof(int));
    int* off      = (int*)alloc((NN + 1) * sizeof(int));
    int* cursor   = (int*)alloc(NN * sizeof(int));
    int* csr      = (int*)alloc(ET * sizeof(int));
    float* ssrc   = (float*)alloc((size_t)NN * NH * sizeof(float));
    float* sdst   = (float*)alloc((size_t)NN * NH * sizeof(float));
    float* hbuf   = (float*)alloc((size_t)NN * FD * sizeof(float));
    float* abuf   = (float*)alloc((size_t)NN * FD * sizeof(float));
    float* pooled = (float*)alloc((size_t)NG * FD * sizeof(float));

    // tier B: main-GEMM planes (measured working in round 4)
    const int KT1 = (IN_DIM + 31) / 32;   // 41
    const int KT2 = FD / 32;              // 256
    const size_t sz_xp  = (size_t)(NN / 128) * KT1 * 4096;   // ushorts
    const size_t sz_w1p = (size_t)(FD / 128) * KT1 * 4096;
    const size_t sz_w2p = (size_t)(FD / 128) * KT2 * 4096;
    const size_t sz_h2p = (size_t)(NN / 128) * KT2 * 4096;
    unsigned short* xH  = (unsigned short*)alloc(sz_xp * 2);
    unsigned short* xL  = (unsigned short*)alloc(sz_xp * 2);
    unsigned short* w1H = (unsigned short*)alloc(sz_w1p * 2);
    unsigned short* w1L = (unsigned short*)alloc(sz_w1p * 2);
    unsigned short* w2H = (unsigned short*)alloc(sz_w2p * 2);
    unsigned short* w2L = (unsigned short*)alloc(sz_w2p * 2);
    unsigned short* h2H = (unsigned short*)alloc(sz_h2p * 2);
    unsigned short* h2L = (unsigned short*)alloc(sz_h2p * 2);
    const bool planes_ok = (size_t)(p - p0) <= ws_size;

    // tier A: attn-as-GEMM extras
    const size_t sz_pp = (size_t)NH * 256 * 4096;            // P-plane ushorts
    const size_t sz_hb = (size_t)(FD / 128) * 32 * 4096;     // Hb-plane ushorts
    int*   csr_dst = (int*)alloc(ET * sizeof(int));
    float* md      = (float*)alloc((size_t)NN * NH * sizeof(float));
    float* dn      = (float*)alloc((size_t)NN * NH * sizeof(float));
    unsigned short* PpH = (unsigned short*)alloc(sz_pp * 2);
    unsigned short* PpL = (unsigned short*)alloc(sz_pp * 2);
    // union: dense fp32 P (67.1 MB) aliases Hb planes (33.6 MB) — disjoint lifetimes
    char* U = alloc((size_t)NH * NN * NN * sizeof(float));
    float* Pf = (float*)U;
    unsigned short* HbH = (unsigned short*)U;
    unsigned short* HbL = HbH + sz_hb;
    const bool attn_ok = planes_ok && (size_t)(p - p0) <= ws_size;

    const int* esrc = ei;        // edge_index[0]
    const int* edst = ei + EE;   // edge_index[1]

    // CSR by dst (self loops appended)
    k_init_counts<<<(NN + 255) / 256, 256, 0, stream>>>(counts);
    k_count<<<(EE + 255) / 256, 256, 0, stream>>>(edst, counts);
    k_scan<<<1, NN, 0, stream>>>(counts, off, cursor);
    if (attn_ok)
        k_fill2<<<(ET + 255) / 256, 256, 0, stream>>>(esrc, edst, off, cursor, csr, csr_dst);
    else
        k_fill<<<(ET + 255) / 256, 256, 0, stream>>>(esrc, edst, off, cursor, csr);

    dim3 gg(FD / 128, NN / 128);     // main GEMM grid
    dim3 ga(FD / 128, NN / 128);     // attn GEMM grid: 64 x 8 (head = bx>>2)
    const int nzero4 = NH * NN * NN / 4;

    // ---- layer 1 ----
    if (planes_ok) {
        k_conv_a<<<(NN / 128) * KT1, 256, 0, stream>>>(x, xH, xL, IN_DIM, KT1);
        k_conv_b<<<(FD / 128) * KT1, 256, 0, stream>>>(W1, w1H, w1L, IN_DIM, FD, KT1);
        k_conv_b<<<(FD / 128) * KT2, 256, 0, stream>>>(W2, w2H, w2L, FD, FD, KT2);
        k_gemm_planes<<<gg, 256, 0, stream>>>(xH, xL, w1H, w1L, hbuf, KT1, FD,
                                              nullptr, 0, 0);
    } else {
        k_gemm_mfma<<<gg, 256, 0, stream>>>(x, W1, hbuf, NN, IN_DIM, FD);
    }
    k_scores<<<NN * NH / 4, 256, 0, stream>>>(hbuf, as1, ad1, ssrc, sdst);
    if (attn_ok) {
        k_stats<<<NN, 256, 0, stream>>>(ssrc, sdst, off, csr, md, dn);
        k_zero4<<<2048, 256, 0, stream>>>((float4*)Pf, nzero4);
        k_scatter<<<(ET + 255) / 256, 256, 0, stream>>>(csr, csr_dst, ssrc, sdst, md, dn, Pf);
        k_conv_pa<<<NH * 256, 256, 0, stream>>>(Pf, PpH, PpL);
        k_conv_b<<<(FD / 128) * 32, 256, 0, stream>>>(hbuf, HbH, HbL, NN, FD, 32);
        k_gemm_planes<<<ga, 256, 0, stream>>>(PpH, PpL, HbH, HbL, abuf, 32, FD,
                                              b1, 1, 1);
    } else {
        k_attn<<<NN, 256, 0, stream>>>(hbuf, ssrc, sdst, off, csr, b1, abuf);
    }

    // ---- layer 2 ----
    if (planes_ok) {
        k_conv_a<<<(NN / 128) * KT2, 256, 0, stream>>>(abuf, h2H, h2L, FD, KT2);
        k_gemm_planes<<<gg, 256, 0, stream>>>(h2H, h2L, w2H, w2L, hbuf, KT2, FD,
                                              nullptr, 0, 0);
    } else {
        k_gemm_mfma<<<gg, 256, 0, stream>>>(abuf, W2, hbuf, NN, FD, FD);
    }
    k_scores<<<NN * NH / 4, 256, 0, stream>>>(hbuf, as2, ad2, ssrc, sdst);
    if (attn_ok) {
        k_stats<<<NN, 256, 0, stream>>>(ssrc, sdst, off, csr, md, dn);
        k_zero4<<<2048, 256, 0, stream>>>((float4*)Pf, nzero4);
        k_scatter<<<(ET + 255) / 256, 256, 0, stream>>>(csr, csr_dst, ssrc, sdst, md, dn, Pf);
        k_conv_pa<<<NH * 256, 256, 0, stream>>>(Pf, PpH, PpL);
        k_conv_b<<<(FD / 128) * 32, 256, 0, stream>>>(hbuf, HbH, HbL, NN, FD, 32);
        k_gemm_planes<<<ga, 256, 0, stream>>>(PpH, PpL, HbH, HbL, abuf, 32, FD,
                                              b2, 1, 1);
    } else {
        k_attn<<<NN, 256, 0, stream>>>(hbuf, ssrc, sdst, off, csr, b2, abuf);
    }

    // pool + head
    k_pool<<<FD / 256, 256, 0, stream>>>(abuf, bat, pooled);
    k_final<<<NG, 256, 0, stream>>>(pooled, lw, lb, (float*)d_out);
}